// Round 3
// baseline (523.004 us; speedup 1.0000x reference)
//
#include <hip/hip_runtime.h>
#include <math.h>

#define Bdim 4
#define Lseq 4096
#define INDIM 512
#define DH 64
#define OUTD 512
#define KSPL 8
#define QSPL 4
#define BL (Bdim * Lseq)
#define QS 0.18033688011112042f   // (1/sqrt(64)) * log2(e): scores land in exp2 domain

typedef _Float16 f16;
typedef _Float16 h8 __attribute__((ext_vector_type(8)));
typedef _Float16 h4 __attribute__((ext_vector_type(4)));
typedef float f4 __attribute__((ext_vector_type(4)));

#define MFMA(a, b, c) __builtin_amdgcn_mfma_f32_16x16x32_f16(a, b, c, 0, 0, 0)

// ---------- transpose + fp16 cast of a [K][N] fp32 weight -> WT[N][K] fp16 ----------
__global__ __launch_bounds__(256) void transpose_w(const float* __restrict__ W,
                                                   f16* __restrict__ WT,
                                                   int K, int N, float scale) {
    int id = blockIdx.x * 256 + threadIdx.x;
    if (id >= K * N) return;
    int n = id / K, k = id % K;
    WT[(size_t)n * K + k] = (f16)(W[(size_t)k * N + n] * scale);
}

// ---------- fused q/k/v projection: x[16384,512] fp32 -> qh/kh/vh fp16 ----------
__global__ __launch_bounds__(256) void qkvh(const float* __restrict__ x,
                                            const f16* __restrict__ WqT,
                                            const f16* __restrict__ WkT,
                                            const f16* __restrict__ WvT,
                                            const float* __restrict__ bq,
                                            const float* __restrict__ bk,
                                            const float* __restrict__ bv,
                                            f16* __restrict__ qh,
                                            f16* __restrict__ kh,
                                            f16* __restrict__ vh) {
    __shared__ __align__(16) f16 xh[64 * 136];
    int t = threadIdx.x;
    int w = t >> 6, lane = t & 63, l15 = lane & 15, quad = lane >> 4;
    size_t row0 = (size_t)blockIdx.x * 64;

    f4 acc[12];
#pragma unroll
    for (int i = 0; i < 12; ++i) acc[i] = (f4){0.f, 0.f, 0.f, 0.f};

    const f16* wbase[12];
#pragma unroll
    for (int nt = 0; nt < 12; ++nt) {
        const f16* Wt = nt < 4 ? WqT : (nt < 8 ? WkT : WvT);
        wbase[nt] = Wt + (size_t)((nt & 3) * 16 + l15) * INDIM + quad * 8;
    }

    int xr = t >> 2, xc = (t & 3) * 4;
    for (int kc = 0; kc < INDIM; kc += 128) {
        __syncthreads();
#pragma unroll
        for (int i = 0; i < 8; ++i) {
            float4 v = *(const float4*)(x + (row0 + xr) * INDIM + kc + xc + i * 16);
            h4 p = {(f16)v.x, (f16)v.y, (f16)v.z, (f16)v.w};
            *(h4*)(xh + xr * 136 + xc + i * 16) = p;
        }
        __syncthreads();
#pragma unroll
        for (int ks = 0; ks < 4; ++ks) {
            h8 a = *(const h8*)(xh + (w * 16 + l15) * 136 + ks * 32 + quad * 8);
#pragma unroll
            for (int nt = 0; nt < 12; ++nt) {
                h8 bf = *(const h8*)(wbase[nt] + kc + ks * 32);
                acc[nt] = MFMA(a, bf, acc[nt]);
            }
        }
    }
#pragma unroll
    for (int nt = 0; nt < 12; ++nt) {
        int n = (nt & 3) * 16 + l15;
        f16* dst;
        float bias;
        if (nt < 4)      { dst = qh; bias = bq[n] * QS; }
        else if (nt < 8) { dst = kh; bias = bk[n]; }
        else             { dst = vh; bias = bv[n]; }
#pragma unroll
        for (int r = 0; r < 4; ++r) {
            size_t row = row0 + w * 16 + quad * 4 + r;
            dst[row * DH + n] = (f16)(acc[nt][r] + bias);
        }
    }
}

// ---------- vh [b][k][d] -> vt [b][d][k] (fp16) ----------
__global__ __launch_bounds__(256) void vtrans(const f16* __restrict__ vh,
                                              f16* __restrict__ vt) {
    __shared__ __align__(16) f16 tile[64 * 72];
    int t = threadIdx.x;
    int b = blockIdx.y, k0 = blockIdx.x * 64;
    int row = t >> 2, c16 = (t & 3) * 16;
    const h8* src = (const h8*)(vh + ((size_t)b * Lseq + k0 + row) * DH + c16);
    *(h8*)(tile + row * 72 + c16) = src[0];
    *(h8*)(tile + row * 72 + c16 + 8) = src[1];
    __syncthreads();
    int d = t >> 2, kq = (t & 3) * 16;
#pragma unroll
    for (int i = 0; i < 2; ++i) {
        h8 p;
#pragma unroll
        for (int j = 0; j < 8; ++j) p[j] = tile[(kq + i * 8 + j) * 72 + d];
        *(h8*)(vt + ((size_t)b * DH + d) * Lseq + k0 + kq + i * 8) = p;
    }
}

// ---------- pass 1: lsum[k] = sum_q exp2(s) via MFMA, barrier-free ----------
__global__ __launch_bounds__(256) void col_stats(const f16* __restrict__ qh,
                                                 const f16* __restrict__ kh,
                                                 float* __restrict__ lsum) {
    int t = threadIdx.x, w = t >> 6, lane = t & 63, l15 = lane & 15, quad = lane >> 4;
    int b = blockIdx.y;
    int k16 = blockIdx.x * 64 + w * 16;
    size_t qbase = (size_t)blockIdx.z * (Lseq / QSPL);

    const h8* kr = (const h8*)(kh + ((size_t)b * Lseq + k16 + l15) * DH + quad * 8);
    h8 a0 = kr[0], a1 = kr[4];
    f4 lp = {0.f, 0.f, 0.f, 0.f};
    const f16* qb = qh + ((size_t)b * Lseq + qbase) * DH;
#pragma unroll 4
    for (int q = 0; q < Lseq / QSPL; q += 16) {
        const h8* qr = (const h8*)(qb + (size_t)(q + l15) * DH + quad * 8);
        h8 b0 = qr[0], b1 = qr[4];
        f4 c = {0.f, 0.f, 0.f, 0.f};
        c = MFMA(a0, b0, c);
        c = MFMA(a1, b1, c);
#pragma unroll
        for (int r = 0; r < 4; ++r) lp[r] += exp2f(c[r]);
    }
#pragma unroll
    for (int r = 0; r < 4; ++r) {
        float v = lp[r];
        v += __shfl_xor(v, 1);
        v += __shfl_xor(v, 2);
        v += __shfl_xor(v, 4);
        v += __shfl_xor(v, 8);
        if (l15 == 0) atomicAdd(&lsum[(size_t)b * Lseq + k16 + quad * 4 + r], v);
    }
}

__global__ __launch_bounds__(256) void rlk(const float* __restrict__ lsum,
                                           float* __restrict__ rl) {
    int i = blockIdx.x * 256 + threadIdx.x;
    rl[i] = 1.0f / lsum[i];
}

// ---------- pass 2: S = K·Q^T (regs = consecutive k), A write + PV, barrier-free ----------
__global__ __launch_bounds__(256) void attn_pv(const f16* __restrict__ qh,
                                               const f16* __restrict__ kh,
                                               const f16* __restrict__ vt,
                                               const float* __restrict__ rl,
                                               float* __restrict__ att,
                                               f16* __restrict__ opart) {
    __shared__ __align__(16) f16 ew[4][32 * 72];
    int t = threadIdx.x, w = t >> 6, lane = t & 63, l15 = lane & 15, quad = lane >> 4;
    int b = blockIdx.y, split = blockIdx.z;
    int q0 = blockIdx.x * 128 + w * 32;

    h8 bq[2][2];
#pragma unroll
    for (int mt = 0; mt < 2; ++mt) {
        const h8* qp = (const h8*)(qh + ((size_t)b * Lseq + q0 + mt * 16 + l15) * DH + quad * 8);
        bq[mt][0] = qp[0];
        bq[mt][1] = qp[4];
    }
    f4 o[2][4];
#pragma unroll
    for (int mt = 0; mt < 2; ++mt)
#pragma unroll
        for (int nt = 0; nt < 4; ++nt) o[mt][nt] = (f4){0.f, 0.f, 0.f, 0.f};

    f16* e = ew[w];
    const f16* khb = kh + (size_t)b * Lseq * DH;
    const f16* vtb = vt + (size_t)b * DH * Lseq;
    const float* rlb = rl + (size_t)b * Lseq;
    float* attb = att + ((size_t)b * Lseq + q0) * Lseq;

    for (int kt = 0; kt < Lseq / KSPL; kt += 64) {
        int kb = split * (Lseq / KSPL) + kt;
        h8 ak[4][2];
        f4 rlv[4];
#pragma unroll
        for (int nt = 0; nt < 4; ++nt) {
            const h8* kp = (const h8*)(khb + (size_t)(kb + nt * 16 + l15) * DH + quad * 8);
            ak[nt][0] = kp[0];
            ak[nt][1] = kp[4];
            rlv[nt] = *(const f4*)(rlb + kb + nt * 16 + quad * 4);
        }
#pragma unroll
        for (int mt = 0; mt < 2; ++mt)
#pragma unroll
            for (int nt = 0; nt < 4; ++nt) {
                f4 c = {0.f, 0.f, 0.f, 0.f};
                c = MFMA(ak[nt][0], bq[mt][0], c);
                c = MFMA(ak[nt][1], bq[mt][1], c);
                f4 av;
                h4 ah;
#pragma unroll
                for (int r = 0; r < 4; ++r) {
                    float a = exp2f(c[r]) * rlv[nt][r];
                    av[r] = a;
                    ah[r] = (f16)a;
                }
                *(f4*)(attb + (size_t)(mt * 16 + l15) * Lseq + kb + nt * 16 + quad * 4) = av;
                *(h4*)(e + (mt * 16 + l15) * 72 + nt * 16 + quad * 4) = ah;
            }
        // PV: O[q][d] += A[q,k]·V[k,d]  (A from per-wave LDS, V^T from global/L2)
        h8 ae[2][2];
#pragma unroll
        for (int mt = 0; mt < 2; ++mt) {
            const f16* ep = e + (mt * 16 + l15) * 72 + quad * 8;
            ae[mt][0] = *(const h8*)ep;
            ae[mt][1] = *(const h8*)(ep + 32);
        }
#pragma unroll
        for (int nt = 0; nt < 4; ++nt) {
            const h8* vp = (const h8*)(vtb + (size_t)(nt * 16 + l15) * Lseq + kb + quad * 8);
            h8 b0 = vp[0], b1 = vp[4];
#pragma unroll
            for (int mt = 0; mt < 2; ++mt) {
                o[mt][nt] = MFMA(ae[mt][0], b0, o[mt][nt]);
                o[mt][nt] = MFMA(ae[mt][1], b1, o[mt][nt]);
            }
        }
    }
#pragma unroll
    for (int mt = 0; mt < 2; ++mt)
#pragma unroll
        for (int nt = 0; nt < 4; ++nt)
#pragma unroll
            for (int r = 0; r < 4; ++r) {
                size_t qrow = (size_t)b * Lseq + q0 + mt * 16 + quad * 4 + r;
                opart[((size_t)split * BL + qrow) * DH + nt * 16 + l15] = (f16)o[mt][nt][r];
            }
}

// ---------- split-reduce + output projection via MFMA ----------
__global__ __launch_bounds__(256) void oproj(const f16* __restrict__ opart,
                                             const f16* __restrict__ WoT,
                                             const float* __restrict__ bo,
                                             float* __restrict__ out) {
    int t = threadIdx.x, w = t >> 6, lane = t & 63, l15 = lane & 15, quad = lane >> 4;
    size_t row0 = (size_t)blockIdx.x * 64 + w * 16;

    h8 a0 = (h8)(f16)0.f, a1 = (h8)(f16)0.f;
#pragma unroll
    for (int sp = 0; sp < KSPL; ++sp) {
        const h8* op = (const h8*)(opart + ((size_t)sp * BL + row0 + l15) * DH + quad * 8);
        a0 += op[0];
        a1 += op[4];
    }
#pragma unroll
    for (int nt = 0; nt < OUTD / 16; ++nt) {
        const h8* wp = (const h8*)(WoT + (size_t)(nt * 16 + l15) * DH + quad * 8);
        h8 b0 = wp[0], b1 = wp[4];
        f4 c = {0.f, 0.f, 0.f, 0.f};
        c = MFMA(a0, b0, c);
        c = MFMA(a1, b1, c);
        float bias = bo[nt * 16 + l15];
#pragma unroll
        for (int r = 0; r < 4; ++r)
            out[(row0 + quad * 4 + r) * OUTD + nt * 16 + l15] = c[r] + bias;
    }
}

extern "C" void kernel_launch(void* const* d_in, const int* in_sizes, int n_in,
                              void* d_out, int out_size, void* d_ws, size_t ws_size,
                              hipStream_t stream) {
    const float* x  = (const float*)d_in[0];
    const float* Wq = (const float*)d_in[1];
    const float* bq = (const float*)d_in[2];
    const float* Wk = (const float*)d_in[3];
    const float* bk = (const float*)d_in[4];
    const float* Wv = (const float*)d_in[5];
    const float* bv = (const float*)d_in[6];
    const float* Wo = (const float*)d_in[7];
    const float* bo = (const float*)d_in[8];

    float* out = (float*)d_out;                   // [B,L,OUTD]
    float* att = out + (size_t)BL * OUTD;         // [B,L,L]

    char* ws = (char*)d_ws;
    f16*   qh   = (f16*)(ws);                                   // 2 MB
    f16*   kh   = (f16*)(ws + (size_t)(2 << 20));               // 2 MB
    f16*   vh   = (f16*)(ws + (size_t)(4 << 20));               // 2 MB
    f16*   vt   = (f16*)(ws + (size_t)(6 << 20));               // 2 MB
    f16*   WqT  = (f16*)(ws + (size_t)(8 << 20));               // 64 KB
    f16*   WkT  = (f16*)(ws + (size_t)(8 << 20) + (1 << 16));
    f16*   WvT  = (f16*)(ws + (size_t)(8 << 20) + (2 << 16));
    f16*   WoT  = (f16*)(ws + (size_t)(8 << 20) + (3 << 16));
    float* lsum = (float*)(ws + (size_t)(8 << 20) + (4 << 16));
    float* rlw  = (float*)(ws + (size_t)(8 << 20) + (5 << 16));
    f16*   opart = (f16*)(ws + (size_t)(9 << 20));              // 16 MB

    transpose_w<<<dim3(128), 256, 0, stream>>>(Wq, WqT, INDIM, DH, QS);
    transpose_w<<<dim3(128), 256, 0, stream>>>(Wk, WkT, INDIM, DH, 1.0f);
    transpose_w<<<dim3(128), 256, 0, stream>>>(Wv, WvT, INDIM, DH, 1.0f);
    transpose_w<<<dim3(128), 256, 0, stream>>>(Wo, WoT, DH, OUTD, 1.0f);
    qkvh<<<dim3(BL / 64), 256, 0, stream>>>(x, WqT, WkT, WvT, bq, bk, bv, qh, kh, vh);
    vtrans<<<dim3(Lseq / 64, Bdim), 256, 0, stream>>>(vh, vt);
    hipMemsetAsync(lsum, 0, (size_t)BL * sizeof(float), stream);
    col_stats<<<dim3(Lseq / 64, Bdim, QSPL), 256, 0, stream>>>(qh, kh, lsum);
    rlk<<<dim3(BL / 256), 256, 0, stream>>>(lsum, rlw);
    attn_pv<<<dim3(Lseq / 128, Bdim, KSPL), 256, 0, stream>>>(qh, kh, vt, rlw, att, opart);
    oproj<<<dim3(BL / 64), 256, 0, stream>>>(opart, WoT, bo, out);
}